// Round 8
// baseline (157.420 us; speedup 1.0000x reference)
//
#include <hip/hip_runtime.h>

#define NTOK 49
#define NH 4
#define HD 32
#define CIN 384
#define NW 64
#define NPAD 64
#define SCALE_F 0.1767766952966369f

typedef _Float16 f16x8 __attribute__((ext_vector_type(8)));
typedef float f32x16 __attribute__((ext_vector_type(16)));
typedef __fp16 fp16x2 __attribute__((ext_vector_type(2)));

__device__ __forceinline__ unsigned int pkh(float a, float b) {
    fp16x2 h = __builtin_amdgcn_cvt_pkrtz(a, b);
    return __builtin_bit_cast(unsigned int, h);
}

__device__ __forceinline__ f16x8 mkfrag(const float4& a, const float4& b) {
    uint4 u;
    u.x = pkh(a.x, a.y);
    u.y = pkh(a.z, a.w);
    u.z = pkh(b.x, b.y);
    u.w = pkh(b.z, b.w);
    return __builtin_bit_cast(f16x8, u);
}

// cmM[w*4+h][i][j] = mask[h][i][j] + rot[w][i][j], padded to 64x64:
// j>=49 -> -1e30 (kills padded keys), i>=49 -> 0.
__global__ __launch_bounds__(64) void prep_cmask(
    const float* __restrict__ mask,
    const float* __restrict__ rot,
    float* __restrict__ cmM)
{
    const int wh = blockIdx.x >> 2;     // w*4 + h
    const int iq = blockIdx.x & 3;      // i-quarter
    const int w = wh >> 2, h = wh & 3;
    const int j = threadIdx.x;          // 0..63
    for (int ii = 0; ii < 16; ++ii) {
        const int i = iq * 16 + ii;
        float v;
        if (j >= NTOK) v = -1e30f;
        else if (i >= NTOK) v = 0.f;
        else v = mask[(h * NTOK + i) * NTOK + j] + rot[(w * NTOK + i) * NTOK + j];
        cmM[((size_t)wh * NPAD + i) * NPAD + j] = v;
    }
}

// One wave per (b,h). No LDS, no barrier: A/B fragments loaded directly from
// global (guarded float4 pairs) + cvt_pkrtz. S^T = K*Q^T via mfma_32x32x16_f16
// (C: col=i=lane&31, row=j=(r&3)+8*(r>>2)+4*hl+32*jt). Softmax lane-local +
// shfl_xor(32). cm fused post-MFMA; P packed to f16 with 1/sum folded.
template<bool USE_CM>
__global__ __launch_bounds__(64) void win_attn_mfma(
    const float* __restrict__ qkv,
    const float* __restrict__ mask,
    const float* __restrict__ rot,
    const float* __restrict__ cmM,
    float* __restrict__ out)
{
    const int h = blockIdx.x & 3;
    const int b = blockIdx.x >> 2;
    const int w = b & (NW - 1);
    const int lane = threadIdx.x;
    const int l31 = lane & 31;
    const int hl = lane >> 5;

    const float* base = qkv + (size_t)b * (NTOK * CIN) + h * HD;
    const float4 z4 = make_float4(0.f, 0.f, 0.f, 0.f);

    // ---- K/Q fragments straight from global (guarded; padded rows = 0) ----
    // lane holds row (l31+32t), 8 consecutive floats at d = ks*16 + hl*8.
    f16x8 ka[2][2], qa[2][2];   // [tile][ks]
    #pragma unroll
    for (int t = 0; t < 2; ++t) {
        const int row = l31 + 32 * t;
        const bool ok = row < NTOK;
        const float* qp = base + (size_t)row * CIN + hl * 8;
        const float* kp = qp + 128;
        #pragma unroll
        for (int ks = 0; ks < 2; ++ks) {
            const float4 q0 = ok ? *reinterpret_cast<const float4*>(qp + ks * 16)     : z4;
            const float4 q1 = ok ? *reinterpret_cast<const float4*>(qp + ks * 16 + 4) : z4;
            const float4 k0 = ok ? *reinterpret_cast<const float4*>(kp + ks * 16)     : z4;
            const float4 k1 = ok ? *reinterpret_cast<const float4*>(kp + ks * 16 + 4) : z4;
            const float4 qs0 = make_float4(q0.x * SCALE_F, q0.y * SCALE_F, q0.z * SCALE_F, q0.w * SCALE_F);
            const float4 qs1 = make_float4(q1.x * SCALE_F, q1.y * SCALE_F, q1.z * SCALE_F, q1.w * SCALE_F);
            qa[t][ks] = mkfrag(qs0, qs1);
            ka[t][ks] = mkfrag(k0, k1);
        }
    }

    // ---- S^T = K * Q^T ----
    f32x16 acc[2][2];           // [it][jt]
    __builtin_amdgcn_s_setprio(1);
    #pragma unroll
    for (int it = 0; it < 2; ++it) {
        #pragma unroll
        for (int jt = 0; jt < 2; ++jt) {
            f32x16 a;
            #pragma unroll
            for (int r = 0; r < 16; ++r) a[r] = 0.f;
            a = __builtin_amdgcn_mfma_f32_32x32x16_f16(ka[jt][0], qa[it][0], a, 0, 0, 0);
            a = __builtin_amdgcn_mfma_f32_32x32x16_f16(ka[jt][1], qa[it][1], a, 0, 0, 0);
            acc[it][jt] = a;
        }
    }
    __builtin_amdgcn_s_setprio(0);

    // ---- V B-fragments (issued here; latency rides under cm-add + softmax) ----
    uint4 vb[4];
    {
        const float* vbase = qkv + (size_t)b * (NTOK * CIN) + 256 + h * HD + l31;
        #pragma unroll
        for (int ks = 0; ks < 4; ++ks) {
            unsigned dd[4];
            #pragma unroll
            for (int ep = 0; ep < 4; ++ep) {
                const int j0 = 16 * ks + 8 * hl + 2 * ep;
                const float v0 = (j0     < NTOK) ? vbase[(size_t)j0 * CIN]       : 0.f;
                const float v1 = (j0 + 1 < NTOK) ? vbase[(size_t)(j0 + 1) * CIN] : 0.f;
                dd[ep] = pkh(v0, v1);
            }
            vb[ks] = make_uint4(dd[0], dd[1], dd[2], dd[3]);
        }
    }

    // ---- fused mask add (float4 straight into acc; cmM is L2-warm) ----
    #pragma unroll
    for (int it = 0; it < 2; ++it) {
        const int i = l31 + 32 * it;
        if (USE_CM) {
            const float* cmRow = cmM + ((size_t)(w * 4 + h) * NPAD + i) * NPAD + 4 * hl;
            #pragma unroll
            for (int jt = 0; jt < 2; ++jt) {
                #pragma unroll
                for (int rq = 0; rq < 4; ++rq) {
                    const float4 c = *reinterpret_cast<const float4*>(&cmRow[32 * jt + 8 * rq]);
                    acc[it][jt][4 * rq + 0] += c.x;
                    acc[it][jt][4 * rq + 1] += c.y;
                    acc[it][jt][4 * rq + 2] += c.z;
                    acc[it][jt][4 * rq + 3] += c.w;
                }
            }
        } else {
            #pragma unroll
            for (int jt = 0; jt < 2; ++jt) {
                #pragma unroll
                for (int r = 0; r < 16; ++r) {
                    const int j = (r & 3) + 8 * (r >> 2) + 4 * hl + 32 * jt;
                    float v;
                    if (j >= NTOK) v = -1e30f;
                    else if (i >= NTOK) v = 0.f;
                    else v = mask[(h * NTOK + i) * NTOK + j] + rot[(w * NTOK + i) * NTOK + j];
                    acc[it][jt][r] += v;
                }
            }
        }
    }

    // ---- softmax + immediate pack to f16 P-fragments (1/sum folded) ----
    uint4 pa[2][4];   // [it][ks]
    #pragma unroll
    for (int it = 0; it < 2; ++it) {
        float m = -3e38f;
        #pragma unroll
        for (int jt = 0; jt < 2; ++jt) {
            #pragma unroll
            for (int r = 0; r < 16; ++r) m = fmaxf(m, acc[it][jt][r]);
        }
        m = fmaxf(m, __shfl_xor(m, 32));
        float s = 0.f;
        #pragma unroll
        for (int jt = 0; jt < 2; ++jt) {
            #pragma unroll
            for (int r = 0; r < 16; ++r) {
                const float e = __expf(acc[it][jt][r] - m);
                acc[it][jt][r] = e;
                s += e;
            }
        }
        s += __shfl_xor(s, 32);
        const float inv = 1.f / s;

        #pragma unroll
        for (int ks = 0; ks < 4; ++ks) {
            const int jt = ks >> 1;
            const int r8 = 8 * (ks & 1);
            const unsigned lo0 = pkh(acc[it][jt][r8 + 0] * inv, acc[it][jt][r8 + 1] * inv);
            const unsigned lo1 = pkh(acc[it][jt][r8 + 2] * inv, acc[it][jt][r8 + 3] * inv);
            const unsigned hi0 = pkh(acc[it][jt][r8 + 4] * inv, acc[it][jt][r8 + 5] * inv);
            const unsigned hi1 = pkh(acc[it][jt][r8 + 6] * inv, acc[it][jt][r8 + 7] * inv);
            const unsigned x0 = hl ? lo0 : hi0;
            const unsigned x1 = hl ? lo1 : hi1;
            const unsigned y0 = (unsigned)__shfl_xor((int)x0, 32);
            const unsigned y1 = (unsigned)__shfl_xor((int)x1, 32);
            uint4 pu;
            pu.x = hl ? y0 : lo0;
            pu.y = hl ? y1 : lo1;
            pu.z = hl ? hi0 : y0;
            pu.w = hl ? hi1 : y1;
            pa[it][ks] = pu;
        }
    }

    // ---- O = P * V ----
    f32x16 oacc[2];
    #pragma unroll
    for (int it = 0; it < 2; ++it) {
        #pragma unroll
        for (int r = 0; r < 16; ++r) oacc[it][r] = 0.f;
    }
    __builtin_amdgcn_s_setprio(1);
    #pragma unroll
    for (int ks = 0; ks < 4; ++ks) {
        const f16x8 vbk = __builtin_bit_cast(f16x8, vb[ks]);
        #pragma unroll
        for (int it = 0; it < 2; ++it) {
            const f16x8 pak = __builtin_bit_cast(f16x8, pa[it][ks]);
            oacc[it] = __builtin_amdgcn_mfma_f32_32x32x16_f16(pak, vbk, oacc[it], 0, 0, 0);
        }
    }
    __builtin_amdgcn_s_setprio(0);

    // ---- store: O[i][d], d = l31 ----
    float* obase = out + (size_t)b * NTOK * (NH * HD) + h * HD + l31;
    #pragma unroll
    for (int it = 0; it < 2; ++it) {
        #pragma unroll
        for (int r = 0; r < 16; ++r) {
            const int io = (r & 3) + 8 * (r >> 2) + 4 * hl + 32 * it;
            if (io < NTOK) obase[(size_t)io * (NH * HD)] = oacc[it][r];
        }
    }
}

extern "C" void kernel_launch(void* const* d_in, const int* in_sizes, int n_in,
                              void* d_out, int out_size, void* d_ws, size_t ws_size,
                              hipStream_t stream) {
    const float* qkv  = (const float*)d_in[0];
    const float* mask = (const float*)d_in[1];
    const float* rot  = (const float*)d_in[2];
    float* out = (float*)d_out;

    const int Btot = in_sizes[0] / (NTOK * CIN);  // 4096
    dim3 grid(Btot * NH);

    const size_t cm_bytes = (size_t)NW * NH * NPAD * NPAD * sizeof(float);  // 4 MiB
    if (ws_size >= cm_bytes && d_ws != nullptr) {
        float* cmM = (float*)d_ws;
        prep_cmask<<<dim3(NW * NH * 4), 64, 0, stream>>>(mask, rot, cmM);
        win_attn_mfma<true><<<grid, 64, 0, stream>>>(qkv, mask, rot, cmM, out);
    } else {
        win_attn_mfma<false><<<grid, 64, 0, stream>>>(qkv, mask, rot, nullptr, out);
    }
}

// Round 9
// 106.865 us; speedup vs baseline: 1.4731x; 1.4731x over previous
//
#include <hip/hip_runtime.h>

#define NTOK 49
#define NH 4
#define HD 32
#define CIN 384
#define NW 64
#define NPAD 64
#define SCALE_F 0.1767766952966369f

typedef _Float16 f16x8 __attribute__((ext_vector_type(8)));
typedef float f32x16 __attribute__((ext_vector_type(16)));
typedef __fp16 fp16x2 __attribute__((ext_vector_type(2)));

__device__ __forceinline__ unsigned int pkh(float a, float b) {
    fp16x2 h = __builtin_amdgcn_cvt_pkrtz(a, b);
    return __builtin_bit_cast(unsigned int, h);
}

// cmT[w*4+h][j][i] = mask[h][i][j] + rot[w][i][j], padded to 64x64,
// j>=49 -> -1e30 (kills padded keys in softmax), i>=49 -> 0.
__global__ __launch_bounds__(64) void prep_cmask(
    const float* __restrict__ mask,
    const float* __restrict__ rot,
    float* __restrict__ cmT)
{
    const int wh = blockIdx.x;          // w*4 + h
    const int w = wh >> 2, h = wh & 3;
    const int i = threadIdx.x;          // 0..63
    for (int j = 0; j < NPAD; ++j) {
        float v;
        if (j >= NTOK) v = -1e30f;
        else if (i >= NTOK) v = 0.f;
        else v = mask[(h * NTOK + i) * NTOK + j] + rot[(w * NTOK + i) * NTOK + j];
        cmT[((size_t)wh * NPAD + j) * NPAD + i] = v;
    }
}

// Two waves per (b,h): wave it (=threadIdx.x>>6) owns query-half it.
// S^T = K*Q^T via mfma_32x32x16_f16 (C: col=i=lane&31, row=j=(r&3)+8*(r>>2)+4*hl+32*jt).
// Softmax lane-local + shfl_xor(32). Identical lane math to the proven R5 kernel;
// only the 'it' loop became the wave index (halves per-wave chain + liveness).
template<bool USE_CM>
__global__ __launch_bounds__(128) void win_attn_mfma(
    const float* __restrict__ qkv,
    const float* __restrict__ mask,
    const float* __restrict__ rot,
    const float* __restrict__ cmT,
    float* __restrict__ out)
{
    const int h = blockIdx.x & 3;
    const int b = blockIdx.x >> 2;
    const int w = b & (NW - 1);
    const int tid = threadIdx.x;
    const int it = tid >> 6;            // wave id = query-half
    const int lane = tid & 63;
    const int l31 = lane & 31;
    const int hl = lane >> 5;

    __shared__ _Float16 Qs[NPAD * HD];   // rows >= 49 zeroed
    __shared__ _Float16 Ks[NPAD * HD];

    const float* base = qkv + (size_t)b * (NTOK * CIN) + h * HD;

    // ---- stage Q (pre-scaled) and K as f16 into LDS (both waves cooperate) ----
    #pragma unroll
    for (int t4 = 0; t4 < 4; ++t4) {
        const int idx = tid + t4 * 128;    // 0..511
        const int n = idx >> 3;            // row 0..63
        const int c = idx & 7;             // float4 chunk
        float4 fq = make_float4(0.f, 0.f, 0.f, 0.f);
        float4 fk = fq;
        if (n < NTOK) {
            const float* p = base + n * CIN + c * 4;
            fq = *reinterpret_cast<const float4*>(p);
            fk = *reinterpret_cast<const float4*>(p + 128);
        }
        uint2 uq, uk;
        uq.x = pkh(fq.x * SCALE_F, fq.y * SCALE_F);
        uq.y = pkh(fq.z * SCALE_F, fq.w * SCALE_F);
        uk.x = pkh(fk.x, fk.y);
        uk.y = pkh(fk.z, fk.w);
        *reinterpret_cast<uint2*>(&Qs[n * HD + c * 4]) = uq;
        *reinterpret_cast<uint2*>(&Ks[n * HD + c * 4]) = uk;
    }

    // ---- combined mask values for this wave's query half (pre-barrier, as R5) ----
    const int i = l31 + 32 * it;
    float cm[2][16];
    #pragma unroll
    for (int jt = 0; jt < 2; ++jt) {
        #pragma unroll
        for (int r = 0; r < 16; ++r) {
            const int j = (r & 3) + 8 * (r >> 2) + 4 * hl + 32 * jt;
            if (USE_CM) {
                cm[jt][r] = cmT[((size_t)(w * 4 + h) * NPAD + j) * NPAD + i];
            } else {
                float v;
                if (j >= NTOK) v = -1e30f;
                else if (i >= NTOK) v = 0.f;
                else v = mask[(h * NTOK + i) * NTOK + j] + rot[(w * NTOK + i) * NTOK + j];
                cm[jt][r] = v;
            }
        }
    }

    __syncthreads();

    // ---- fragments from LDS: K both tiles, Q own half only ----
    f16x8 ka[2][2], qa[2];   // ka[tile][ks], qa[ks]
    #pragma unroll
    for (int t = 0; t < 2; ++t) {
        #pragma unroll
        for (int ks = 0; ks < 2; ++ks) {
            ka[t][ks] = *reinterpret_cast<const f16x8*>(&Ks[(l31 + 32 * t) * HD + ks * 16 + hl * 8]);
        }
    }
    #pragma unroll
    for (int ks = 0; ks < 2; ++ks) {
        qa[ks] = *reinterpret_cast<const f16x8*>(&Qs[(l31 + 32 * it) * HD + ks * 16 + hl * 8]);
    }

    // ---- S^T = K * Q^T for this half ----
    f32x16 acc[2];           // [jt]
    #pragma unroll
    for (int jt = 0; jt < 2; ++jt) {
        f32x16 a;
        #pragma unroll
        for (int r = 0; r < 16; ++r) a[r] = 0.f;
        a = __builtin_amdgcn_mfma_f32_32x32x16_f16(ka[jt][0], qa[0], a, 0, 0, 0);
        a = __builtin_amdgcn_mfma_f32_32x32x16_f16(ka[jt][1], qa[1], a, 0, 0, 0);
        acc[jt] = a;
    }

    // ---- + mask, softmax over j (32 lane-local + lane^32 partner) ----
    float m = -3e38f;
    #pragma unroll
    for (int jt = 0; jt < 2; ++jt) {
        #pragma unroll
        for (int r = 0; r < 16; ++r) {
            acc[jt][r] += cm[jt][r];
            m = fmaxf(m, acc[jt][r]);
        }
    }
    m = fmaxf(m, __shfl_xor(m, 32));
    float s = 0.f;
    #pragma unroll
    for (int jt = 0; jt < 2; ++jt) {
        #pragma unroll
        for (int r = 0; r < 16; ++r) {
            const float e = __expf(acc[jt][r] - m);
            acc[jt][r] = e;
            s += e;
        }
    }
    s += __shfl_xor(s, 32);
    const float inv = 1.f / s;
    #pragma unroll
    for (int jt = 0; jt < 2; ++jt) {
        #pragma unroll
        for (int r = 0; r < 16; ++r) acc[jt][r] *= inv;
    }

    // ---- O = P * V (V fragments from global, as R5) ----
    f32x16 oacc;
    #pragma unroll
    for (int r = 0; r < 16; ++r) oacc[r] = 0.f;

    #pragma unroll
    for (int ks = 0; ks < 4; ++ks) {
        // V B-fragment: lane holds V[16ks+8hl+e][d=l31]
        unsigned int vd[4];
        #pragma unroll
        for (int ep = 0; ep < 4; ++ep) {
            const int j0 = 16 * ks + 8 * hl + 2 * ep;
            float v0 = 0.f, v1 = 0.f;
            if (j0 < NTOK)
                v0 = qkv[((size_t)b * NTOK + j0) * CIN + 256 + h * HD + l31];
            if (j0 + 1 < NTOK)
                v1 = qkv[((size_t)b * NTOK + j0 + 1) * CIN + 256 + h * HD + l31];
            vd[ep] = pkh(v0, v1);
        }
        uint4 vu = make_uint4(vd[0], vd[1], vd[2], vd[3]);
        const f16x8 vb = __builtin_bit_cast(f16x8, vu);

        const int jt = ks >> 1;
        const int r8 = 8 * (ks & 1);
        // pack own j-pairs; exchange the half the partner needs (lane ^ 32)
        const unsigned lo0 = pkh(acc[jt][r8 + 0], acc[jt][r8 + 1]);
        const unsigned lo1 = pkh(acc[jt][r8 + 2], acc[jt][r8 + 3]);
        const unsigned hi0 = pkh(acc[jt][r8 + 4], acc[jt][r8 + 5]);
        const unsigned hi1 = pkh(acc[jt][r8 + 6], acc[jt][r8 + 7]);
        const unsigned x0 = hl ? lo0 : hi0;
        const unsigned x1 = hl ? lo1 : hi1;
        const unsigned y0 = (unsigned)__shfl_xor((int)x0, 32);
        const unsigned y1 = (unsigned)__shfl_xor((int)x1, 32);
        uint4 pu;
        pu.x = hl ? y0 : lo0;
        pu.y = hl ? y1 : lo1;
        pu.z = hl ? hi0 : y0;
        pu.w = hl ? hi1 : y1;
        const f16x8 pa = __builtin_bit_cast(f16x8, pu);
        oacc = __builtin_amdgcn_mfma_f32_32x32x16_f16(pa, vb, oacc, 0, 0, 0);
    }

    // ---- store this half: O[i][d], d = l31 ----
    float* obase = out + (size_t)b * NTOK * (NH * HD) + h * HD + l31;
    #pragma unroll
    for (int r = 0; r < 16; ++r) {
        const int io = (r & 3) + 8 * (r >> 2) + 4 * hl + 32 * it;
        if (io < NTOK) obase[(size_t)io * (NH * HD)] = oacc[r];
    }
}

extern "C" void kernel_launch(void* const* d_in, const int* in_sizes, int n_in,
                              void* d_out, int out_size, void* d_ws, size_t ws_size,
                              hipStream_t stream) {
    const float* qkv  = (const float*)d_in[0];
    const float* mask = (const float*)d_in[1];
    const float* rot  = (const float*)d_in[2];
    float* out = (float*)d_out;

    const int Btot = in_sizes[0] / (NTOK * CIN);  // 4096
    dim3 grid(Btot * NH);

    const size_t cm_bytes = (size_t)NW * NH * NPAD * NPAD * sizeof(float);  // 4 MiB
    if (ws_size >= cm_bytes && d_ws != nullptr) {
        float* cmT = (float*)d_ws;
        prep_cmask<<<dim3(NW * NH), 64, 0, stream>>>(mask, rot, cmT);
        win_attn_mfma<true><<<grid, 128, 0, stream>>>(qkv, mask, rot, cmT, out);
    } else {
        win_attn_mfma<false><<<grid, 128, 0, stream>>>(qkv, mask, rot, nullptr, out);
    }
}